// Round 8
// baseline (5048.754 us; speedup 1.0000x reference)
//
#include <hip/hip_runtime.h>

// WeatherLSTM: B=256, T=128, I=64, H=2048, O=24
// R8: per-step kernels, tile 128x64, 128 threads (2 waves), sub-tile 64x64 per
// wave via mfma_32x32x16 -> per-CU LDS reads halved vs R6 (the measured wall).
// k-major LDS layout [kc][row] = conflict-free ds_read_b128 (2-way only).
// Depth-5 pipeline over 6 bufs, one raw s_barrier/kt, counted vmcnt.

#define NB 256
#define NH 2048
#define NI 64
#define NK 2112
#define NPK 8192
#define NSTEPS 151
#define NO 24

typedef __bf16 bf16x8 __attribute__((ext_vector_type(8)));
typedef short short8 __attribute__((ext_vector_type(8)));
typedef float f32x4 __attribute__((ext_vector_type(4)));
typedef float f32x16 __attribute__((ext_vector_type(16)));
typedef unsigned short u16;

__device__ __forceinline__ u16 f2bf(float f) {
  union { float f; unsigned u; } v; v.f = f;
  unsigned r = v.u + 0x7FFFu + ((v.u >> 16) & 1u);  // RNE
  return (u16)(r >> 16);
}

__device__ __forceinline__ void gload16(const void* g, void* l) {
  __builtin_amdgcn_global_load_lds(
      (const __attribute__((address_space(1))) unsigned int*)g,
      (__attribute__((address_space(3))) unsigned int*)l, 16, 0, 0);
}

__device__ __forceinline__ float sigmoidf_(float x) { return 1.f / (1.f + __expf(-x)); }
__device__ __forceinline__ float tanhf_(float x) {
  x = fminf(15.f, fmaxf(-15.f, x));
  float e = __expf(2.f * x);
  return (e - 1.f) / (e + 1.f);
}

// ---- pack [Wh;Wx] fp32 [k][4H] -> Wp bf16 [p][k], p = u*4+g
__global__ __launch_bounds__(256) void wl_pack_w(const float* __restrict__ Wx,
                                                 const float* __restrict__ Wh,
                                                 u16* __restrict__ Wp) {
  __shared__ float s[64][65];
  const int j0 = blockIdx.x * 64, k0 = blockIdx.y * 64;
  const int tid = threadIdx.x;
  const int jl = tid & 63, kg = tid >> 6;
#pragma unroll
  for (int it = 0; it < 16; ++it) {
    int kl = it * 4 + kg;
    int k = k0 + kl, j = j0 + jl;
    float v = (k < NH) ? Wh[(size_t)k * NPK + j] : Wx[(size_t)(k - NH) * NPK + j];
    s[kl][jl] = v;
  }
  __syncthreads();
  int j = j0 + jl;
  int p = (j & (NH - 1)) * 4 + (j >> 11);
  short8 v0, v1;
#pragma unroll
  for (int e = 0; e < 8; ++e) {
    v0[e] = (short)f2bf(s[kg * 16 + e][jl]);
    v1[e] = (short)f2bf(s[kg * 16 + 8 + e][jl]);
  }
  short8* dst = (short8*)(Wp + (size_t)p * NK + k0 + kg * 16);
  dst[0] = v0;
  dst[1] = v1;
}

__global__ __launch_bounds__(256) void wl_bsum(const float* __restrict__ bx,
                                               const float* __restrict__ bh,
                                               float* __restrict__ bsum) {
  int p = blockIdx.x * 256 + threadIdx.x;
  int j = (p & 3) * NH + (p >> 2);
  bsum[p] = bx[j] + bh[j];
}

__global__ __launch_bounds__(256) void wl_xall(const float* __restrict__ trains,
                                               const float* __restrict__ dec,
                                               const float* __restrict__ Win,
                                               const float* __restrict__ b_in,
                                               u16* __restrict__ xall) {
  int idx = blockIdx.x * 256 + threadIdx.x;
  int i = idx & 63;
  int b = (idx >> 6) & 255;
  int t = idx >> 14;
  float v;
  if (t < 128) v = trains[((size_t)b * 128 + t) * 64 + i];
  else         v = dec[b * 23 + (t - 128)] * Win[i] + b_in[i];
  xall[idx] = f2bf(v);
}

// ---- one step. 256 blocks x 128 threads (2 waves). Tile 128 rows x 64 cols.
// cs = (bid&7)*16 + ((bid>>3)&15), rh = bid>>7; bid & bid+128 share cs + XCD.
// LDS buf (24KB): A [kc 0..7][row 0..127][16B] | B [kc 0..7][col 0..63][16B].
__global__ __launch_bounds__(128) void wl_step(const u16* __restrict__ Wpg,
                                               const float* __restrict__ bsum,
                                               const u16* __restrict__ xall,
                                               u16* __restrict__ hcat,  // 2 bufs
                                               float* __restrict__ c_t, // [u][b]
                                               float* __restrict__ ypart,
                                               const float* __restrict__ Wout,
                                               int t) {
  __shared__ char arena[147456];  // 6 bufs x 24KB; epilogue gtile 32KB (bufs 0-1)

  const int bid = blockIdx.x;
  const int cs = (bid & 7) * 16 + ((bid >> 3) & 15);  // col-slice 0..127
  const int rh = bid >> 7;                            // row half 0/1
  const int p0 = cs * 64, u0 = cs * 16, b0 = rh * 128;

  const int tid = threadIdx.x;
  const int wv = tid >> 6, lane = tid & 63;           // wv 0..1
  const int l31 = lane & 31, lh = lane >> 5;          // mfma 32x32 lane split

  const u16* __restrict__ hin = hcat + (size_t)(t & 1) * NB * NH;
  u16* __restrict__ hout = hcat + (size_t)((t + 1) & 1) * NB * NH;

  f32x16 acc00 = {}, acc01 = {}, acc10 = {}, acc11 = {};

  // stage tile kt (K=64) into buf: A 16KB (16 chunks) + B 8KB (8 chunks);
  // 12 DMA issues per wave. Dest bases wave-uniform, global src per-lane.
  auto stage = [&](int kt, int buf) {
    char* const base = arena + buf * 24576;
    const u16* asrc; int astr;
    if (kt < 32) { asrc = hin + (size_t)b0 * NH + kt * 64; astr = NH; }
    else         { asrc = xall + ((size_t)t * NB + b0) * NI; astr = NI; }
#pragma unroll
    for (int i = 0; i < 8; ++i) {
      int j = wv * 8 + i;                // chunk 0..15
      int kc = j >> 1, r8 = j & 1;
      int row = r8 * 64 + lane;
      gload16(asrc + (size_t)row * astr + kc * 8, base + kc * 2048 + r8 * 1024);
    }
    const u16* bsrc = Wpg + (size_t)(p0 + lane) * NK + kt * 64;
#pragma unroll
    for (int i = 0; i < 4; ++i) {
      int kc = wv * 4 + i;               // chunk 0..7
      gload16(bsrc + kc * 8, base + 16384 + kc * 1024);
    }
  };

  auto compute = [&](int buf) {
    const char* Ab = arena + buf * 24576;
    const char* Bb = Ab + 16384;
#pragma unroll
    for (int s = 0; s < 4; ++s) {        // k16 steps
      int kc = s * 2 + lh;
      bf16x8 a0 = *(const bf16x8*)(Ab + kc * 2048 + (wv * 64 + l31) * 16);
      bf16x8 a1 = *(const bf16x8*)(Ab + kc * 2048 + (wv * 64 + 32 + l31) * 16);
      bf16x8 bf0 = *(const bf16x8*)(Bb + kc * 1024 + l31 * 16);
      bf16x8 bf1 = *(const bf16x8*)(Bb + kc * 1024 + (32 + l31) * 16);
      acc00 = __builtin_amdgcn_mfma_f32_32x32x16_bf16(a0, bf0, acc00, 0, 0, 0);
      acc01 = __builtin_amdgcn_mfma_f32_32x32x16_bf16(a0, bf1, acc01, 0, 0, 0);
      acc10 = __builtin_amdgcn_mfma_f32_32x32x16_bf16(a1, bf0, acc10, 0, 0, 0);
      acc11 = __builtin_amdgcn_mfma_f32_32x32x16_bf16(a1, bf1, acc11, 0, 0, 0);
    }
  };

  // prologue: 5 tiles in flight (60 loads/wave, vmcnt max 63 ok)
  stage(0, 0); stage(1, 1); stage(2, 2); stage(3, 3); stage(4, 4);
  for (int kt = 0; kt < 33; ++kt) {
    // wait until this wave's 12 loads for tile kt complete
    if (kt <= 28)      asm volatile("s_waitcnt vmcnt(48)" ::: "memory");
    else if (kt == 29) asm volatile("s_waitcnt vmcnt(36)" ::: "memory");
    else if (kt == 30) asm volatile("s_waitcnt vmcnt(24)" ::: "memory");
    else if (kt == 31) asm volatile("s_waitcnt vmcnt(12)" ::: "memory");
    else               asm volatile("s_waitcnt vmcnt(0)" ::: "memory");
    asm volatile("s_barrier" ::: "memory");  // both waves: tile kt resident AND
                                             // compute(kt-1) done (buf reuse safe)
    if (kt + 5 <= 32) {
      int sb = kt + 5 - ((kt + 5 >= 6) ? 6 : 0); sb = (kt + 5) % 6;
      stage(kt + 5, sb);
    }
    compute(kt % 6);
  }

  // ---- spill acc -> gtile [row 0..127][16B chunk ul ^ (row&15)], 32KB
  __syncthreads();
  {
    char* gt = arena;
#pragma unroll
    for (int rb = 0; rb < 2; ++rb)
#pragma unroll
      for (int cb = 0; cb < 2; ++cb) {
        const f32x16& a = rb ? (cb ? acc11 : acc10) : (cb ? acc01 : acc00);
#pragma unroll
        for (int r = 0; r < 16; ++r) {
          int row = wv * 64 + rb * 32 + (r & 3) + 8 * (r >> 2) + 4 * lh;
          int col = cb * 32 + l31;
          *(float*)(gt + row * 256 + (((col >> 2) ^ (row & 15)) << 4) +
                    (col & 3) * 4) = a[r];
        }
      }
  }
  __syncthreads();

  // ---- gates + state: thread = batch row bl (0..127), 16 units in-thread
  {
    const int bl = tid;
    const int bg = b0 + bl;
    const bool emit = (t >= 127);
    float yacc = 0.f;
    short8 hva, hvb;
#pragma unroll
    for (int ul = 0; ul < 16; ++ul) {
      f32x4 g = *(const f32x4*)(arena + bl * 256 + ((ul ^ (bl & 15)) << 4));
      const float4 bs = *(const float4*)(bsum + p0 + ul * 4);
      float si = sigmoidf_(g[0] + bs.x);
      float sf = sigmoidf_(g[1] + bs.y);
      float so = sigmoidf_(g[2] + bs.z);
      float tc = tanhf_(g[3] + bs.w);
      size_t ci = (size_t)(u0 + ul) * NB + bg;
      float cn = sf * c_t[ci] + si * tc;
      float h = so * tanhf_(cn);
      c_t[ci] = cn;
      if (ul < 8) hva[ul] = (short)f2bf(h); else hvb[ul - 8] = (short)f2bf(h);
      if (emit) yacc += h * Wout[u0 + ul];
    }
    *(short8*)(hout + (size_t)bg * NH + u0) = hva;
    *(short8*)(hout + (size_t)bg * NH + u0 + 8) = hvb;
    if (emit) ypart[((size_t)(t - 127) * 128 + cs) * NB + bg] = yacc;
  }
}

// ---- y[b][j] = bout + sum_{cs<128} ypart[j][cs][b]
__global__ __launch_bounds__(256) void wl_finy(const float* __restrict__ ypart,
                                               const float* __restrict__ bout,
                                               float* __restrict__ out) {
  int j = blockIdx.x;
  int b = threadIdx.x;
  const float* yp = ypart + (size_t)j * 128 * NB;
  float s = bout[0];
#pragma unroll 8
  for (int i = 0; i < 128; ++i) s += yp[i * NB + b];
  out[b * NO + j] = s;
}

extern "C" void kernel_launch(void* const* d_in, const int* in_sizes, int n_in,
                              void* d_out, int out_size, void* d_ws, size_t ws_size,
                              hipStream_t stream) {
  const float* trains = (const float*)d_in[0];
  const float* dec    = (const float*)d_in[1];
  const float* Wx     = (const float*)d_in[2];
  const float* bx     = (const float*)d_in[3];
  const float* Wh     = (const float*)d_in[4];
  const float* bh     = (const float*)d_in[5];
  const float* Win    = (const float*)d_in[6];
  const float* b_in   = (const float*)d_in[7];
  const float* Wout   = (const float*)d_in[8];
  const float* bout   = (const float*)d_in[9];
  float* out = (float*)d_out;
  char* ws = (char*)d_ws;

  u16*   Wp    = (u16*)(ws);                  // 34,603,008
  float* bsum  = (float*)(ws + 34603008);     //     32,768
  u16*   xall  = (u16*)(ws + 34635776);       //  4,947,968 -> 39,583,744
  u16*   hcat  = (u16*)(ws + 39583744);       //  4,194,304 -> 43,778,048
  float* c_t   = (float*)(ws + 43778048);     //  2,097,152 -> 45,875,200
  float* ypart = (float*)(ws + 45875200);     //  3,014,656 -> 48,889,856

  // zero hcat (both bufs) + c_t in one memset (contiguous)
  (void)hipMemsetAsync(ws + 39583744, 0, 6291456, stream);
  wl_pack_w<<<dim3(128, 33), 256, 0, stream>>>(Wx, Wh, Wp);
  wl_bsum<<<32, 256, 0, stream>>>(bx, bh, bsum);
  wl_xall<<<(NSTEPS * NB * NI) / 256, 256, 0, stream>>>(trains, dec, Win, b_in, xall);
  for (int t = 0; t < NSTEPS; ++t)
    wl_step<<<256, 128, 0, stream>>>(Wp, bsum, xall, hcat, c_t, ypart, Wout, t);
  wl_finy<<<NO, 256, 0, stream>>>(ypart, bout, out);
}

// Round 9
// 3470.245 us; speedup vs baseline: 1.4549x; 1.4549x over previous
//
#include <hip/hip_runtime.h>

// WeatherLSTM: B=256, T=128, I=64, H=2048, O=24
// R9: per-step kernels, tile 128x64. R7's line-efficient staging (8 rows x
// 128B per DMA instr) + 4 waves with 64x32 sub-tiles via mfma_32x32x16
// (block LDS reads 80KB -> 32KB per tile, the R7 wall). Depth-5 pipeline,
// 6 x 24KB LDS bufs, one raw s_barrier per k-iter, counted vmcnt.

#define NB 256
#define NH 2048
#define NI 64
#define NK 2112
#define NPK 8192
#define NSTEPS 151
#define NO 24

typedef __bf16 bf16x8 __attribute__((ext_vector_type(8)));
typedef short short8 __attribute__((ext_vector_type(8)));
typedef float f32x4 __attribute__((ext_vector_type(4)));
typedef float f32x16 __attribute__((ext_vector_type(16)));
typedef unsigned short u16;

__device__ __forceinline__ u16 f2bf(float f) {
  union { float f; unsigned u; } v; v.f = f;
  unsigned r = v.u + 0x7FFFu + ((v.u >> 16) & 1u);  // RNE
  return (u16)(r >> 16);
}

__device__ __forceinline__ void gload16(const void* g, void* l) {
  __builtin_amdgcn_global_load_lds(
      (const __attribute__((address_space(1))) unsigned int*)g,
      (__attribute__((address_space(3))) unsigned int*)l, 16, 0, 0);
}

__device__ __forceinline__ float sigmoidf_(float x) { return 1.f / (1.f + __expf(-x)); }
__device__ __forceinline__ float tanhf_(float x) {
  x = fminf(15.f, fmaxf(-15.f, x));
  float e = __expf(2.f * x);
  return (e - 1.f) / (e + 1.f);
}

// ---- pack [Wh;Wx] fp32 [k][4H] -> Wp bf16 [p][k], p = u*4+g
__global__ __launch_bounds__(256) void wl_pack_w(const float* __restrict__ Wx,
                                                 const float* __restrict__ Wh,
                                                 u16* __restrict__ Wp) {
  __shared__ float s[64][65];
  const int j0 = blockIdx.x * 64, k0 = blockIdx.y * 64;
  const int tid = threadIdx.x;
  const int jl = tid & 63, kg = tid >> 6;
#pragma unroll
  for (int it = 0; it < 16; ++it) {
    int kl = it * 4 + kg;
    int k = k0 + kl, j = j0 + jl;
    float v = (k < NH) ? Wh[(size_t)k * NPK + j] : Wx[(size_t)(k - NH) * NPK + j];
    s[kl][jl] = v;
  }
  __syncthreads();
  int j = j0 + jl;
  int p = (j & (NH - 1)) * 4 + (j >> 11);
  short8 v0, v1;
#pragma unroll
  for (int e = 0; e < 8; ++e) {
    v0[e] = (short)f2bf(s[kg * 16 + e][jl]);
    v1[e] = (short)f2bf(s[kg * 16 + 8 + e][jl]);
  }
  short8* dst = (short8*)(Wp + (size_t)p * NK + k0 + kg * 16);
  dst[0] = v0;
  dst[1] = v1;
}

__global__ __launch_bounds__(256) void wl_bsum(const float* __restrict__ bx,
                                               const float* __restrict__ bh,
                                               float* __restrict__ bsum) {
  int p = blockIdx.x * 256 + threadIdx.x;
  int j = (p & 3) * NH + (p >> 2);
  bsum[p] = bx[j] + bh[j];
}

__global__ __launch_bounds__(256) void wl_xall(const float* __restrict__ trains,
                                               const float* __restrict__ dec,
                                               const float* __restrict__ Win,
                                               const float* __restrict__ b_in,
                                               u16* __restrict__ xall) {
  int idx = blockIdx.x * 256 + threadIdx.x;
  int i = idx & 63;
  int b = (idx >> 6) & 255;
  int t = idx >> 14;
  float v;
  if (t < 128) v = trains[((size_t)b * 128 + t) * 64 + i];
  else         v = dec[b * 23 + (t - 128)] * Win[i] + b_in[i];
  xall[idx] = f2bf(v);
}

// ---- one step. 256 blocks x 256 threads (4 waves). Tile 128 rows x 64 cols.
// cs = (bid&7)*16 + ((bid>>3)&15), rh = bid>>7; bid & bid+128 share cs + XCD.
// Wave (wm,wn) = (wv>>1, wv&1) owns rows [wm*64,+64) x cols [wn*32,+32).
__global__ __launch_bounds__(256) void wl_step(const u16* __restrict__ Wpg,
                                               const float* __restrict__ bsum,
                                               const u16* __restrict__ xall,
                                               u16* __restrict__ hcat,  // 2 bufs
                                               float* __restrict__ c_t, // [u][b]
                                               float* __restrict__ ypart,
                                               const float* __restrict__ Wout,
                                               int t) {
  __shared__ char arena[147456];  // 6 bufs x (A 16K | B 8K); epilogue gtile 32KB

  const int bid = blockIdx.x;
  const int cs = (bid & 7) * 16 + ((bid >> 3) & 15);  // col-slice 0..127
  const int rh = bid >> 7;                            // row half 0/1
  const int p0 = cs * 64, u0 = cs * 16, b0 = rh * 128;

  const int tid = threadIdx.x;
  const int wv = tid >> 6, lane = tid & 63;           // wv 0..3
  const int wm = wv >> 1, wn = wv & 1;                // wave sub-tile coords
  const int l31 = lane & 31, lh = lane >> 5;
  const int srow = lane >> 3, sc = lane & 7;          // staging: 8 rows x 8 chunks/KB
  const int g8 = sc ^ srow;                           // pre-swizzled chunk

  const u16* __restrict__ hin = hcat + (size_t)(t & 1) * NB * NH;
  u16* __restrict__ hout = hcat + (size_t)((t + 1) & 1) * NB * NH;

  f32x16 acc0 = {}, acc1 = {};   // 2 m-blocks (32 rows each) x 32 cols

  // stage tile kt into buf: A 128x64 (16KB, 16 chunks) + B 64x64 (8KB, 8 chunks)
  // 6 DMA issues/wave; each instr = 8 rows x 128B contiguous (16 cache lines).
  auto stage = [&](int kt, int buf) {
    char* const base = arena + buf * 24576;
    const u16* asrc; int astr;
    if (kt < 32) { asrc = hin + (size_t)b0 * NH + kt * 64; astr = NH; }
    else         { asrc = xall + ((size_t)t * NB + b0) * NI; astr = NI; }
#pragma unroll
    for (int i = 0; i < 4; ++i) {
      int qa = wv * 4 + i;                 // 1KB chunk 0..15
      int row = qa * 8 + srow;             // 0..127
      gload16(asrc + (size_t)row * astr + g8 * 8, base + qa * 1024);
    }
    const u16* bsrc = Wpg + (size_t)p0 * NK + kt * 64;
#pragma unroll
    for (int i = 0; i < 2; ++i) {
      int qb = wv * 2 + i;                 // 0..7
      int col = qb * 8 + srow;             // 0..63
      gload16(bsrc + (size_t)col * NK + g8 * 8, base + 16384 + qb * 1024);
    }
  };

  auto compute = [&](int buf) {
    const char* Ab = arena + buf * 24576;
    const char* Bb = Ab + 16384;
#pragma unroll
    for (int s = 0; s < 4; ++s) {          // four k16 steps
      const int c8 = s * 2 + lh;           // 16B index within 128B row
      int bcol = wn * 32 + l31;
      bf16x8 bfr = *(const bf16x8*)(Bb + bcol * 128 + ((c8 ^ (bcol & 7)) << 4));
      int ar0 = wm * 64 + l31;
      bf16x8 a0 = *(const bf16x8*)(Ab + ar0 * 128 + ((c8 ^ (ar0 & 7)) << 4));
      bf16x8 a1 = *(const bf16x8*)(Ab + (ar0 + 32) * 128 + ((c8 ^ (ar0 & 7)) << 4));
      acc0 = __builtin_amdgcn_mfma_f32_32x32x16_bf16(a0, bfr, acc0, 0, 0, 0);
      acc1 = __builtin_amdgcn_mfma_f32_32x32x16_bf16(a1, bfr, acc1, 0, 0, 0);
    }
  };

  // prologue: 5 tiles in flight (30 loads/wave)
  stage(0, 0); stage(1, 1); stage(2, 2); stage(3, 3); stage(4, 4);
  for (int kt = 0; kt < 33; ++kt) {
    // wait until this wave's 6 loads for tile kt complete
    if (kt <= 28)      asm volatile("s_waitcnt vmcnt(24)" ::: "memory");
    else if (kt == 29) asm volatile("s_waitcnt vmcnt(18)" ::: "memory");
    else if (kt == 30) asm volatile("s_waitcnt vmcnt(12)" ::: "memory");
    else if (kt == 31) asm volatile("s_waitcnt vmcnt(6)" ::: "memory");
    else               asm volatile("s_waitcnt vmcnt(0)" ::: "memory");
    asm volatile("s_barrier" ::: "memory");  // all waves: tile kt resident AND
                                             // compute(kt-1) done (buf reuse safe)
    if (kt + 5 <= 32) stage(kt + 5, (kt + 5) % 6);
    compute(kt % 6);
  }

  // ---- spill acc -> gtile [col 0..63][chunk(row>>2) 0..31] swizzled, 32KB
  __syncthreads();  // vmcnt already 0; all waves past compute(32)
  {
    const int col = wn * 32 + l31;
#pragma unroll
    for (int mb = 0; mb < 2; ++mb) {
      const f32x16& a = mb ? acc1 : acc0;
#pragma unroll
      for (int q = 0; q < 4; ++q) {
        f32x4 v = {a[q * 4 + 0], a[q * 4 + 1], a[q * 4 + 2], a[q * 4 + 3]};
        int chunk = wm * 16 + mb * 8 + q * 2 + lh;  // (row)>>2
        *(f32x4*)(arena + col * 512 + ((chunk ^ (col & 7)) << 4)) = v;
      }
    }
  }
  __syncthreads();

  // ---- gates + state: thread -> (row bl 0..127, unit-group ug of 8 units)
  {
    const int bl = tid & 127, ug = tid >> 7;  // ug 0..1
    const int bg = b0 + bl;
    const bool emit = (t >= 127);
    float yacc = 0.f;
    short8 hv;
#pragma unroll
    for (int j = 0; j < 8; ++j) {
      int ul = ug * 8 + j;                 // local unit 0..15
      float g[4];
#pragma unroll
      for (int gi = 0; gi < 4; ++gi) {
        int col = ul * 4 + gi;
        g[gi] = *(const float*)(arena + col * 512 +
                                (((bl >> 2) ^ (col & 7)) << 4) + (bl & 3) * 4);
      }
      const float4 bs = *(const float4*)(bsum + p0 + ul * 4);
      float si = sigmoidf_(g[0] + bs.x);
      float sf = sigmoidf_(g[1] + bs.y);
      float so = sigmoidf_(g[2] + bs.z);
      float tc = tanhf_(g[3] + bs.w);
      size_t ci = (size_t)(u0 + ul) * NB + bg;
      float cn = sf * c_t[ci] + si * tc;
      float h = so * tanhf_(cn);
      c_t[ci] = cn;
      hv[j] = (short)f2bf(h);
      if (emit) yacc += h * Wout[u0 + ul];
    }
    *(short8*)(hout + (size_t)bg * NH + u0 + ug * 8) = hv;  // 16B store
    if (emit) ypart[((size_t)(t - 127) * 256 + cs * 2 + ug) * NB + bg] = yacc;
  }
}

// ---- y[b][j] = bout + sum_{s<256} ypart[j][s][b]
__global__ __launch_bounds__(256) void wl_finy(const float* __restrict__ ypart,
                                               const float* __restrict__ bout,
                                               float* __restrict__ out) {
  int j = blockIdx.x;
  int b = threadIdx.x;
  const float* yp = ypart + (size_t)j * 256 * NB;
  float s = bout[0];
#pragma unroll 8
  for (int i = 0; i < 256; ++i) s += yp[i * NB + b];
  out[b * NO + j] = s;
}

extern "C" void kernel_launch(void* const* d_in, const int* in_sizes, int n_in,
                              void* d_out, int out_size, void* d_ws, size_t ws_size,
                              hipStream_t stream) {
  const float* trains = (const float*)d_in[0];
  const float* dec    = (const float*)d_in[1];
  const float* Wx     = (const float*)d_in[2];
  const float* bx     = (const float*)d_in[3];
  const float* Wh     = (const float*)d_in[4];
  const float* bh     = (const float*)d_in[5];
  const float* Win    = (const float*)d_in[6];
  const float* b_in   = (const float*)d_in[7];
  const float* Wout   = (const float*)d_in[8];
  const float* bout   = (const float*)d_in[9];
  float* out = (float*)d_out;
  char* ws = (char*)d_ws;

  u16*   Wp    = (u16*)(ws);                  // 34,603,008
  float* bsum  = (float*)(ws + 34603008);     //     32,768
  u16*   xall  = (u16*)(ws + 34635776);       //  4,947,968 -> 39,583,744
  u16*   hcat  = (u16*)(ws + 39583744);       //  4,194,304 -> 43,778,048
  float* c_t   = (float*)(ws + 43778048);     //  2,097,152 -> 45,875,200
  float* ypart = (float*)(ws + 45875200);     //  6,291,456 -> 52,166,656

  // zero hcat (both bufs) + c_t in one contiguous memset
  (void)hipMemsetAsync(ws + 39583744, 0, 6291456, stream);
  wl_pack_w<<<dim3(128, 33), 256, 0, stream>>>(Wx, Wh, Wp);
  wl_bsum<<<32, 256, 0, stream>>>(bx, bh, bsum);
  wl_xall<<<(NSTEPS * NB * NI) / 256, 256, 0, stream>>>(trains, dec, Win, b_in, xall);
  for (int t = 0; t < NSTEPS; ++t)
    wl_step<<<256, 256, 0, stream>>>(Wp, bsum, xall, hcat, c_t, ypart, Wout, t);
  wl_finy<<<NO, 256, 0, stream>>>(ypart, bout, out);
}